// Round 1
// baseline (149.830 us; speedup 1.0000x reference)
//
#include <hip/hip_runtime.h>
#include <math.h>

// Pass 1: per-batch joint moments of the 2-D points (double precision),
// then closed-form mean/std(ddof=1) of the S*S pairwise dist_sq values.
//   sum_d  = 2N(S2x+S2y) - 2(S1x^2 + S1y^2)
//   sum_d2 = [2N S4x - 8 S3x S1x + 6 S2x^2] + [same for y]
//          + 2*[2N A22 - 4 A21 S1y - 4 A12 S1x + 2 S2x S2y + 4 A11^2]
// Error vs true sums ~1e-10 relative (double accumulation over 4096 pts),
// far inside the fp32 ulp band of the threshold -> mask decisions match ref.
__global__ void pab_moments_kernel(const float* __restrict__ r,
                                   float* __restrict__ thr_out, int S) {
    const int b = blockIdx.x;
    const float2* emb = (const float2*)r + (size_t)b * S;

    double s[12];
#pragma unroll
    for (int k = 0; k < 12; ++k) s[k] = 0.0;

    for (int idx = threadIdx.x; idx < S; idx += blockDim.x) {
        float2 p = emb[idx];
        double x = (double)p.x, y = (double)p.y;
        double x2 = x * x, y2 = y * y;
        s[0]  += x;        // S1x
        s[1]  += y;        // S1y
        s[2]  += x2;       // S2x
        s[3]  += y2;       // S2y
        s[4]  += x2 * x;   // S3x
        s[5]  += y2 * y;   // S3y
        s[6]  += x2 * x2;  // S4x
        s[7]  += y2 * y2;  // S4y
        s[8]  += x * y;    // A11
        s[9]  += x2 * y;   // A21
        s[10] += x * y2;   // A12
        s[11] += x2 * y2;  // A22
    }

    __shared__ double red[256];
    __shared__ double tot[12];
    for (int k = 0; k < 12; ++k) {
        red[threadIdx.x] = s[k];
        __syncthreads();
        for (int off = blockDim.x >> 1; off > 0; off >>= 1) {
            if ((int)threadIdx.x < off) red[threadIdx.x] += red[threadIdx.x + off];
            __syncthreads();
        }
        if (threadIdx.x == 0) tot[k] = red[0];
        __syncthreads();
    }

    if (threadIdx.x == 0) {
        double N = (double)S;
        double M = N * N;
        double S1x = tot[0], S1y = tot[1], S2x = tot[2], S2y = tot[3];
        double S3x = tot[4], S3y = tot[5], S4x = tot[6], S4y = tot[7];
        double A11 = tot[8], A21 = tot[9], A12 = tot[10], A22 = tot[11];

        double sum_d = 2.0 * N * (S2x + S2y) - 2.0 * (S1x * S1x + S1y * S1y);
        double qx = 2.0 * N * S4x - 8.0 * S3x * S1x + 6.0 * S2x * S2x;
        double qy = 2.0 * N * S4y - 8.0 * S3y * S1y + 6.0 * S2y * S2y;
        double cross = 2.0 * N * A22 - 4.0 * A21 * S1y - 4.0 * A12 * S1x
                     + 2.0 * S2x * S2y + 4.0 * A11 * A11;
        double sum_d2 = qx + qy + 2.0 * cross;

        double mean = sum_d / M;
        double var  = (sum_d2 - sum_d * sum_d / M) / (M - 1.0);  // ddof=1
        double stdv = sqrt(var);
        thr_out[b] = (float)(mean + 1.25 * stdv);
    }
}

// Pass 2: write the full [B,S,S] attention map. One thread -> 4 consecutive
// columns (float4 store, 16B/lane). forward_bias via dx*rsqrt(dist_sq)
// (== cos(atan2(dy,dx)); exactly 1.0 at the zero pair).
__global__ __launch_bounds__(256) void pab_attn_kernel(
        const float* __restrict__ r, const float* __restrict__ thr_ws,
        float* __restrict__ out, int S) {
    const int b = blockIdx.z;
    const int i = blockIdx.y;
    const int j0 = (blockIdx.x * blockDim.x + threadIdx.x) * 4;
    if (j0 >= S) return;

    const float2* emb = (const float2*)r + (size_t)b * S;
    const float2 pi = emb[i];                  // block-uniform -> scalarized
    const float thr = thr_ws[b];

    float4 c0 = *(const float4*)(emb + j0);      // x_{j0},y_{j0},x_{j0+1},y_{j0+1}
    float4 c1 = *(const float4*)(emb + j0 + 2);  // x_{j0+2},y_{j0+2},x_{j0+3},y_{j0+3}
    float xs[4] = {c0.x, c0.z, c1.x, c1.z};
    float ys[4] = {c0.y, c0.w, c1.y, c1.w};

    float4 res;
    float* rp = &res.x;
#pragma unroll
    for (int k = 0; k < 4; ++k) {
        float dx = pi.x - xs[k];
        float dy = pi.y - ys[k];
        float d2 = dx * dx + dy * dy;
        float bias = (d2 > 0.0f) ? (0.5f + 0.5f * dx * rsqrtf(d2)) : 1.0f;
        bool valid = (d2 <= thr) & ((j0 + k) <= i);
        rp[k] = valid ? bias : 0.0f;
    }
    *(float4*)(out + ((size_t)(b * S + i) * S + j0)) = res;
}

extern "C" void kernel_launch(void* const* d_in, const int* in_sizes, int n_in,
                              void* d_out, int out_size, void* d_ws, size_t ws_size,
                              hipStream_t stream) {
    const float* r = (const float*)d_in[0];
    float* out = (float*)d_out;
    float* thr = (float*)d_ws;

    // in_sizes[0] = B*S*2, out_size = B*S*S  ->  S = 2*out_size / in_sizes[0]
    long in0 = in_sizes[0];
    int S = (int)((2L * (long)out_size) / in0);
    int B = (int)(in0 / (2L * S));

    pab_moments_kernel<<<dim3(B), dim3(256), 0, stream>>>(r, thr, S);

    dim3 block(256);
    dim3 grid((S + 1023) / 1024, S, B);
    pab_attn_kernel<<<grid, block, 0, stream>>>(r, thr, out, S);
}

// Round 2
// 144.353 us; speedup vs baseline: 1.0379x; 1.0379x over previous
//
#include <hip/hip_runtime.h>
#include <math.h>

// ---------------------------------------------------------------------------
// Pass 1: per-batch joint moments of the 2-D points (double precision),
// then closed-form mean/std(ddof=1) of the S*S pairwise dist_sq values.
//   sum_d  = 2N(S2x+S2y) - 2(S1x^2 + S1y^2)
//   sum_d2 = [2N S4x - 8 S3x S1x + 6 S2x^2] + [same for y]
//          + 2*[2N A22 - 4 A21 S1y - 4 A12 S1x + 2 S2x S2y + 4 A11^2]
// One 1024-thread block per batch. Reduction: wave-level __shfl_down
// (no barriers) -> 16 wave partials in LDS -> 2 barriers total.
// Replaces the old 192-barrier tree (suspected ~30-50 us of latency).
// ---------------------------------------------------------------------------
__global__ __launch_bounds__(1024) void pab_moments_kernel(
        const float* __restrict__ r, float* __restrict__ thr_out, int S) {
    const int b = blockIdx.x;
    const float2* emb = (const float2*)r + (size_t)b * S;
    const int tid = threadIdx.x;

    double s[12];
#pragma unroll
    for (int k = 0; k < 12; ++k) s[k] = 0.0;

    // 4 points per thread per iteration via two float4 loads.
    for (int idx0 = tid * 4; idx0 < S; idx0 += blockDim.x * 4) {
        float4 c0 = *(const float4*)(emb + idx0);      // p0, p1
        float4 c1 = *(const float4*)(emb + idx0 + 2);  // p2, p3
        float xs[4] = {c0.x, c0.z, c1.x, c1.z};
        float ys[4] = {c0.y, c0.w, c1.y, c1.w};
#pragma unroll
        for (int k = 0; k < 4; ++k) {
            if (idx0 + k >= S) break;
            double x = (double)xs[k], y = (double)ys[k];
            double x2 = x * x, y2 = y * y;
            s[0]  += x;        s[1]  += y;
            s[2]  += x2;       s[3]  += y2;
            s[4]  += x2 * x;   s[5]  += y2 * y;
            s[6]  += x2 * x2;  s[7]  += y2 * y2;
            s[8]  += x * y;    s[9]  += x2 * y;
            s[10] += x * y2;   s[11] += x2 * y2;
        }
    }

    // Wave (64-lane) shuffle reduction — no barriers.
#pragma unroll
    for (int off = 32; off > 0; off >>= 1) {
#pragma unroll
        for (int k = 0; k < 12; ++k)
            s[k] += __shfl_down(s[k], off, 64);
    }

    __shared__ double part[16][12];
    __shared__ double tot[12];
    const int wave = tid >> 6, lane = tid & 63;
    const int nwaves = blockDim.x >> 6;
    if (lane == 0) {
#pragma unroll
        for (int k = 0; k < 12; ++k) part[wave][k] = s[k];
    }
    __syncthreads();
    if (tid < 12) {
        double t = 0.0;
        for (int w = 0; w < nwaves; ++w) t += part[w][tid];
        tot[tid] = t;
    }
    __syncthreads();

    if (tid == 0) {
        double N = (double)S;
        double M = N * N;
        double S1x = tot[0], S1y = tot[1], S2x = tot[2], S2y = tot[3];
        double S3x = tot[4], S3y = tot[5], S4x = tot[6], S4y = tot[7];
        double A11 = tot[8], A21 = tot[9], A12 = tot[10], A22 = tot[11];

        double sum_d = 2.0 * N * (S2x + S2y) - 2.0 * (S1x * S1x + S1y * S1y);
        double qx = 2.0 * N * S4x - 8.0 * S3x * S1x + 6.0 * S2x * S2x;
        double qy = 2.0 * N * S4y - 8.0 * S3y * S1y + 6.0 * S2y * S2y;
        double cross = 2.0 * N * A22 - 4.0 * A21 * S1y - 4.0 * A12 * S1x
                     + 2.0 * S2x * S2y + 4.0 * A11 * A11;
        double sum_d2 = qx + qy + 2.0 * cross;

        double mean = sum_d / M;
        double var  = (sum_d2 - sum_d * sum_d / M) / (M - 1.0);  // ddof=1
        thr_out[b] = (float)(mean + 1.25 * sqrt(var));
    }
}

// ---------------------------------------------------------------------------
// Pass 2: write the full [B,S,S] attention map.
// Tile: 16 rows x 1024 cols per 256-thread block. Column points loaded once
// (2x float4) and reused across 16 rows; row point is a block-uniform scalar
// load per row. 16 float4 stores per thread -> 256 B of output per thread,
// amortizing all addressing/load overhead. Pure store-BW bound.
// forward_bias via 0.5 + 0.5*dx*rsqrt(d2)  (== 0.5*(1+cos(atan2(dy,dx)));
// exactly 1.0 at the zero pair, matching atan2(0,1)=0).
// ---------------------------------------------------------------------------
#define PAB_ROWS 16

__global__ __launch_bounds__(256) void pab_attn_kernel(
        const float* __restrict__ r, const float* __restrict__ thr_ws,
        float* __restrict__ out, int S) {
    const int b = blockIdx.z;
    const int i0 = blockIdx.y * PAB_ROWS;
    const int j0 = (blockIdx.x * blockDim.x + threadIdx.x) * 4;
    if (j0 >= S) return;

    const float2* emb = (const float2*)r + (size_t)b * S;
    const float thr = thr_ws[b];

    float4 c0 = *(const float4*)(emb + j0);      // x_{j0},y_{j0},x_{j0+1},y_{j0+1}
    float4 c1 = *(const float4*)(emb + j0 + 2);  // x_{j0+2},y_{j0+2},x_{j0+3},y_{j0+3}
    const float xs[4] = {c0.x, c0.z, c1.x, c1.z};
    const float ys[4] = {c0.y, c0.w, c1.y, c1.w};

    size_t orow = ((size_t)b * S + i0) * S + j0;
#pragma unroll
    for (int rr = 0; rr < PAB_ROWS; ++rr) {
        const int i = i0 + rr;
        if (i >= S) break;
        const float2 pi = emb[i];  // block-uniform -> scalar load
        float4 res;
        float* rp = &res.x;
#pragma unroll
        for (int k = 0; k < 4; ++k) {
            float dx = pi.x - xs[k];
            float dy = pi.y - ys[k];
            float d2 = fmaf(dx, dx, dy * dy);
            float bias = (d2 > 0.0f) ? fmaf(0.5f * dx, rsqrtf(d2), 0.5f) : 1.0f;
            bool valid = (d2 <= thr) & ((j0 + k) <= i);
            rp[k] = valid ? bias : 0.0f;
        }
        *(float4*)(out + orow) = res;
        orow += S;
    }
}

extern "C" void kernel_launch(void* const* d_in, const int* in_sizes, int n_in,
                              void* d_out, int out_size, void* d_ws, size_t ws_size,
                              hipStream_t stream) {
    const float* r = (const float*)d_in[0];
    float* out = (float*)d_out;
    float* thr = (float*)d_ws;

    // in_sizes[0] = B*S*2, out_size = B*S*S  ->  S = 2*out_size / in_sizes[0]
    long in0 = in_sizes[0];
    int S = (int)((2L * (long)out_size) / in0);
    int B = (int)(in0 / (2L * S));

    pab_moments_kernel<<<dim3(B), dim3(1024), 0, stream>>>(r, thr, S);

    dim3 block(256);
    dim3 grid((S + 1023) / 1024, (S + PAB_ROWS - 1) / PAB_ROWS, B);
    pab_attn_kernel<<<grid, block, 0, stream>>>(r, thr, out, S);
}